// Round 12
// baseline (690.022 us; speedup 1.0000x reference)
//
#include <hip/hip_runtime.h>
#include <hip/hip_cooperative_groups.h>

namespace cg = cooperative_groups;

#define IN_F 256
#define OUT_F 64
#define SORT_CHUNK 4096
#define BKT_SHIFT 7
#define BKT_NODES 128
#define MAX_NB 1024
#define GRID_MAX 1024

typedef __attribute__((ext_vector_type(8))) short short8;
typedef __attribute__((ext_vector_type(4))) float f32x4;

static __device__ __forceinline__ short f2bf(float f) {
    union { float f; unsigned u; } v; v.f = f;
    unsigned r = v.u + 0x7FFFu + ((v.u >> 16) & 1u);  // RNE
    return (short)(r >> 16);
}
static __device__ __forceinline__ float bf2f(short s) {
    return __int_as_float(((unsigned)(unsigned short)s) << 16);
}

// ---- shared device helpers (identical math in mega + fallback) ----

// stage W (fp32, row-major KxN) -> swizzled bf16 LDS (32 KB)
static __device__ __forceinline__ void stage_W(const float* __restrict__ W,
                                               short* Wl, int tid) {
    const int n0 = tid & 63;
    const int kb = tid >> 6;
    #pragma unroll
    for (int K0 = 0; K0 < 64; K0 += 8) {
        const int k0 = kb * 64 + K0;
        short8 v;
        #pragma unroll
        for (int j = 0; j < 8; ++j)
            v[j] = f2bf(W[(k0 + j) * OUT_F + n0]);
        *(short8*)((char*)Wl + n0 * 512 + (((k0 >> 3)) ^ (n0 & 7)) * 16) = v;
    }
}

// one 128-row GEMM tile (4 waves x 32 rows), Wl already staged
static __device__ __forceinline__ void gemm_tile(const float* __restrict__ x,
                                                 const short* Wl,
                                                 const float* __restrict__ bias,
                                                 short* __restrict__ h,
                                                 int rowbase, int nRows, int tid) {
    const int wv = tid >> 6;
    const int l  = tid & 63;
    const int lr = l & 15;
    const int kg = l >> 4;
    const int rb = rowbase + wv * 32;
    if (rb >= nRows) return;
    const int ar0 = min(rb + lr,      nRows - 1);
    const int ar1 = min(rb + 16 + lr, nRows - 1);
    const float* xp0 = x + (size_t)ar0 * IN_F + kg * 8;
    const float* xp1 = x + (size_t)ar1 * IN_F + kg * 8;

    f32x4 acc[2][4];
    #pragma unroll
    for (int m = 0; m < 2; ++m)
        #pragma unroll
        for (int n = 0; n < 4; ++n) acc[m][n] = (f32x4)0.f;

    #pragma unroll
    for (int kt = 0; kt < 8; ++kt) {
        const int K0 = kt * 32;
        float4 a0lo = *(const float4*)(xp0 + K0);
        float4 a0hi = *(const float4*)(xp0 + K0 + 4);
        float4 a1lo = *(const float4*)(xp1 + K0);
        float4 a1hi = *(const float4*)(xp1 + K0 + 4);

        short8 a0, a1;
        a0[0] = f2bf(a0lo.x); a0[1] = f2bf(a0lo.y);
        a0[2] = f2bf(a0lo.z); a0[3] = f2bf(a0lo.w);
        a0[4] = f2bf(a0hi.x); a0[5] = f2bf(a0hi.y);
        a0[6] = f2bf(a0hi.z); a0[7] = f2bf(a0hi.w);
        a1[0] = f2bf(a1lo.x); a1[1] = f2bf(a1lo.y);
        a1[2] = f2bf(a1lo.z); a1[3] = f2bf(a1lo.w);
        a1[4] = f2bf(a1hi.x); a1[5] = f2bf(a1hi.y);
        a1[6] = f2bf(a1hi.z); a1[7] = f2bf(a1hi.w);

        short8 bf[4];
        #pragma unroll
        for (int nt = 0; nt < 4; ++nt) {
            const int col = nt * 16 + lr;
            const int slot = (kt * 4 + kg) ^ (col & 7);
            bf[nt] = *(const short8*)((const char*)Wl + col * 512 + slot * 16);
        }
        #pragma unroll
        for (int nt = 0; nt < 4; ++nt) {
            acc[0][nt] = __builtin_amdgcn_mfma_f32_16x16x32_bf16(a0, bf[nt], acc[0][nt], 0, 0, 0);
            acc[1][nt] = __builtin_amdgcn_mfma_f32_16x16x32_bf16(a1, bf[nt], acc[1][nt], 0, 0, 0);
        }
    }

    #pragma unroll
    for (int m = 0; m < 2; ++m) {
        #pragma unroll
        for (int nt = 0; nt < 4; ++nt) {
            const int col = nt * 16 + lr;
            const float bb = bias[col];
            #pragma unroll
            for (int j = 0; j < 4; ++j) {
                const int r = rb + m * 16 + kg * 4 + j;
                if (r < nRows)
                    h[(size_t)r * OUT_F + col] = f2bf(acc[m][nt][j] + bb);
            }
        }
    }
}

static __device__ __forceinline__ void hist_chunk(const int* __restrict__ dst,
                                                  int* lh, int* __restrict__ counts,
                                                  int cb, int nE, int NB, int nSB,
                                                  int tid) {
    for (int b0 = tid; b0 < NB; b0 += 256) lh[b0] = 0;
    __syncthreads();
    const int base = cb * SORT_CHUNK;
    const int lim = min(nE, base + SORT_CHUNK);
    const int4* d4 = (const int4*)(dst + base);
    const int n4 = (lim - base) >> 2;
    for (int i = tid; i < n4; i += 256) {
        int4 v = d4[i];
        atomicAdd(&lh[v.x >> BKT_SHIFT], 1);
        atomicAdd(&lh[v.y >> BKT_SHIFT], 1);
        atomicAdd(&lh[v.z >> BKT_SHIFT], 1);
        atomicAdd(&lh[v.w >> BKT_SHIFT], 1);
    }
    for (int e = base + (n4 << 2) + tid; e < lim; e += 256)
        atomicAdd(&lh[dst[e] >> BKT_SHIFT], 1);
    __syncthreads();
    for (int b0 = tid; b0 < NB; b0 += 256)
        counts[b0 * nSB + cb] = lh[b0];
    __syncthreads();
}

static __device__ __forceinline__ void bfill_chunk(
        const int* __restrict__ src, const int* __restrict__ dst,
        const float* __restrict__ w, const int* __restrict__ bases,
        const int* __restrict__ part, int2* __restrict__ pack,
        int* cur, int cb, int nE, int NB, int nSB, int tid) {
    for (int b0 = tid; b0 < NB; b0 += 256) {
        int idx = b0 * nSB + cb;
        cur[b0] = bases[idx] + part[idx >> 10];
    }
    __syncthreads();
    const int base = cb * SORT_CHUNK;
    const int lim = min(nE, base + SORT_CHUNK);
    const int4* s4 = (const int4*)(src + base);
    const int4* d4 = (const int4*)(dst + base);
    const float4* w4 = (const float4*)(w + base);
    const int n4 = (lim - base) >> 2;
    for (int i = tid; i < n4; i += 256) {
        int4 s = s4[i]; int4 d = d4[i]; float4 ww = w4[i];
        int p0 = atomicAdd(&cur[d.x >> BKT_SHIFT], 1);
        pack[p0] = make_int2(s.x | ((d.x & (BKT_NODES - 1)) << 17), __float_as_int(ww.x));
        int p1 = atomicAdd(&cur[d.y >> BKT_SHIFT], 1);
        pack[p1] = make_int2(s.y | ((d.y & (BKT_NODES - 1)) << 17), __float_as_int(ww.y));
        int p2 = atomicAdd(&cur[d.z >> BKT_SHIFT], 1);
        pack[p2] = make_int2(s.z | ((d.z & (BKT_NODES - 1)) << 17), __float_as_int(ww.z));
        int p3 = atomicAdd(&cur[d.w >> BKT_SHIFT], 1);
        pack[p3] = make_int2(s.w | ((d.w & (BKT_NODES - 1)) << 17), __float_as_int(ww.w));
    }
    for (int e = base + (n4 << 2) + tid; e < lim; e += 256) {
        int d = dst[e];
        int p = atomicAdd(&cur[d >> BKT_SHIFT], 1);
        pack[p] = make_int2(src[e] | ((d & (BKT_NODES - 1)) << 17),
                            __float_as_int(w[e]));
    }
    __syncthreads();
}

static __device__ __forceinline__ void nsort_bucket(
        const int2* __restrict__ pack, const int* __restrict__ bases,
        const int* __restrict__ part, int2* __restrict__ pack2,
        int* __restrict__ off, int* cnt, int* scn,
        int b, int nRows, int nE, int NB, int nSB, int tid) {
    const int i0 = b * nSB;
    const int segStart = bases[i0] + part[i0 >> 10];
    int segEnd = nE;
    if (b + 1 < NB) {
        int i1 = (b + 1) * nSB;
        segEnd = bases[i1] + part[i1 >> 10];
    }
    if (tid < BKT_NODES) cnt[tid] = 0;
    __syncthreads();
    {
        int e = segStart + tid;
        for (; e + 768 < segEnd; e += 1024) {
            int a0 = pack[e].x, a1 = pack[e + 256].x;
            int a2 = pack[e + 512].x, a3 = pack[e + 768].x;
            atomicAdd(&cnt[(a0 >> 17) & (BKT_NODES - 1)], 1);
            atomicAdd(&cnt[(a1 >> 17) & (BKT_NODES - 1)], 1);
            atomicAdd(&cnt[(a2 >> 17) & (BKT_NODES - 1)], 1);
            atomicAdd(&cnt[(a3 >> 17) & (BKT_NODES - 1)], 1);
        }
        for (; e < segEnd; e += 256)
            atomicAdd(&cnt[(pack[e].x >> 17) & (BKT_NODES - 1)], 1);
    }
    __syncthreads();
    if (tid < BKT_NODES) scn[tid] = cnt[tid];
    __syncthreads();
    for (int d = 1; d < BKT_NODES; d <<= 1) {
        int t = 0;
        if (tid < BKT_NODES && tid >= d) t = scn[tid - d];
        __syncthreads();
        if (tid < BKT_NODES) scn[tid] += t;
        __syncthreads();
    }
    const int node0 = b * BKT_NODES;
    const int ncnt = min(BKT_NODES, nRows - node0);
    if (tid < ncnt)
        off[node0 + tid] = segStart + scn[tid] - cnt[tid];
    if (tid == 0 && node0 + ncnt == nRows)
        off[nRows] = segEnd;
    __syncthreads();
    if (tid < BKT_NODES) cnt[tid] = segStart + scn[tid] - cnt[tid];
    __syncthreads();
    {
        int e = segStart + tid;
        for (; e + 768 < segEnd; e += 1024) {
            int2 p0 = pack[e], p1 = pack[e + 256];
            int2 p2 = pack[e + 512], p3 = pack[e + 768];
            int q0 = atomicAdd(&cnt[(p0.x >> 17) & (BKT_NODES - 1)], 1);
            pack2[q0] = make_int2(p0.x & 0x1FFFF, p0.y);
            int q1 = atomicAdd(&cnt[(p1.x >> 17) & (BKT_NODES - 1)], 1);
            pack2[q1] = make_int2(p1.x & 0x1FFFF, p1.y);
            int q2 = atomicAdd(&cnt[(p2.x >> 17) & (BKT_NODES - 1)], 1);
            pack2[q2] = make_int2(p2.x & 0x1FFFF, p2.y);
            int q3 = atomicAdd(&cnt[(p3.x >> 17) & (BKT_NODES - 1)], 1);
            pack2[q3] = make_int2(p3.x & 0x1FFFF, p3.y);
        }
        for (; e < segEnd; e += 256) {
            int2 p = pack[e];
            int q = atomicAdd(&cnt[(p.x >> 17) & (BKT_NODES - 1)], 1);
            pack2[q] = make_int2(p.x & 0x1FFFF, p.y);
        }
    }
    __syncthreads();
}

static __device__ __forceinline__ float gather_node(
        const ushort* __restrict__ hu, const int2* __restrict__ pack2,
        int e, int end, int lane) {
    float acc = 0.f;
    for (; e + 8 <= end; e += 8) {
        int2 pk[8];
        #pragma unroll
        for (int i = 0; i < 8; ++i) pk[i] = pack2[e + i];
        float hv[8];
        #pragma unroll
        for (int i = 0; i < 8; ++i)
            hv[i] = bf2f((short)hu[(size_t)pk[i].x * OUT_F + lane]);
        #pragma unroll
        for (int i = 0; i < 8; ++i)
            acc = fmaf(__int_as_float(pk[i].y), hv[i], acc);
    }
    for (; e + 4 <= end; e += 4) {
        int2 pk[4];
        #pragma unroll
        for (int i = 0; i < 4; ++i) pk[i] = pack2[e + i];
        #pragma unroll
        for (int i = 0; i < 4; ++i)
            acc = fmaf(__int_as_float(pk[i].y),
                       bf2f((short)hu[(size_t)pk[i].x * OUT_F + lane]), acc);
    }
    for (; e < end; ++e) {
        int2 p = pack2[e];
        acc = fmaf(__int_as_float(p.y),
                   bf2f((short)hu[(size_t)p.x * OUT_F + lane]), acc);
    }
    return acc;
}

// =================== cooperative mega-kernel ===================
__global__ __launch_bounds__(256, 4)
void mega_kernel(const float* __restrict__ x, const int* __restrict__ esrc,
                 const int* __restrict__ edst, const float* __restrict__ ew,
                 const float* __restrict__ W, const float* __restrict__ bias,
                 short* __restrict__ h, int* __restrict__ counts,
                 int* __restrict__ bases, int* __restrict__ part,
                 int2* __restrict__ pack, int2* __restrict__ pack2,
                 int* __restrict__ off, float* __restrict__ out,
                 int nRows, int nE, int NB, int nSB, int nCnt, int nPart) {
    cg::grid_group grid = cg::this_grid();
    __shared__ __align__(16) char smem[32768];
    const int tid = threadIdx.x;
    const int bid = blockIdx.x;
    const int nBlk = gridDim.x;

    // phase 1a: bucket histogram
    for (int cb = bid; cb < nSB; cb += nBlk)
        hist_chunk(edst, (int*)smem, counts, cb, nE, NB, nSB, tid);

    // phase 1b: GEMM
    {
        const int nTiles = (nRows + 127) / 128;
        if (bid < nTiles) {
            short* Wl = (short*)smem;
            stage_W(W, Wl, tid);
            __syncthreads();
            for (int t = bid; t < nTiles; t += nBlk)
                gemm_tile(x, Wl, bias, h, t * 128, nRows, tid);
        }
    }
    grid.sync();

    // phase 2a: scan1
    {
        int* sh = (int*)smem;
        for (int s = bid; s < nPart; s += nBlk) {
            const int base = s * 1024;
            int v[4]; int sum = 0;
            #pragma unroll
            for (int i = 0; i < 4; ++i) {
                int idx = base + tid * 4 + i;
                v[i] = (idx < nCnt) ? counts[idx] : 0;
                sum += v[i];
            }
            sh[tid] = sum;
            __syncthreads();
            for (int d = 1; d < 256; d <<= 1) {
                int val = (tid >= d) ? sh[tid - d] : 0;
                __syncthreads();
                sh[tid] += val;
                __syncthreads();
            }
            if (tid == 255) part[s] = sh[255];
            int run = (tid == 0) ? 0 : sh[tid - 1];
            #pragma unroll
            for (int i = 0; i < 4; ++i) {
                int idx = base + tid * 4 + i;
                if (idx < nCnt) bases[idx] = run;
                run += v[i];
            }
            __syncthreads();
        }
    }
    grid.sync();

    // phase 2b: scan2 (block 0)
    if (bid == 0) {
        int* sh = (int*)smem;
        int v[4]; int sum = 0;
        #pragma unroll
        for (int i = 0; i < 4; ++i) {
            int idx = tid * 4 + i;
            v[i] = (idx < nPart) ? part[idx] : 0;
            sum += v[i];
        }
        sh[tid] = sum;
        __syncthreads();
        for (int d = 1; d < 256; d <<= 1) {
            int val = (tid >= d) ? sh[tid - d] : 0;
            __syncthreads();
            sh[tid] += val;
            __syncthreads();
        }
        int run = (tid == 0) ? 0 : sh[tid - 1];
        #pragma unroll
        for (int i = 0; i < 4; ++i) {
            int idx = tid * 4 + i;
            if (idx < nPart) part[idx] = run;
            run += v[i];
        }
    }
    grid.sync();

    // phase 3: bfill
    for (int cb = bid; cb < nSB; cb += nBlk)
        bfill_chunk(esrc, edst, ew, bases, part, pack, (int*)smem,
                    cb, nE, NB, nSB, tid);
    grid.sync();

    // phase 4: nsort
    {
        int* cnt = (int*)smem;
        int* scn = cnt + BKT_NODES;
        for (int b = bid; b < NB; b += nBlk)
            nsort_bucket(pack, bases, part, pack2, off, cnt, scn,
                         b, nRows, nE, NB, nSB, tid);
    }
    grid.sync();

    // phase 5: ngather
    {
        const int lane = tid & 63;
        const int nW = (nBlk * 256) >> 6;
        const ushort* hu = (const ushort*)h;
        for (int wid = (bid * 256 + tid) >> 6; wid < nRows; wid += nW)
            out[(size_t)wid * OUT_F + lane] =
                gather_node(hu, pack2, off[wid], off[wid + 1], lane);
    }
}

// =================== fallback multi-kernel path ===================
__global__ __launch_bounds__(256, 4)
void fc_bhist_kernel(const float* __restrict__ x, const float* __restrict__ W,
                     const float* __restrict__ bias, short* __restrict__ h,
                     const int* __restrict__ dst, int* __restrict__ counts,
                     int nRows, int nE, int NB, int nSB, int nHist) {
    __shared__ __align__(16) char smem[32768];
    if ((int)blockIdx.x < nHist) {
        hist_chunk(dst, (int*)smem, counts, blockIdx.x, nE, NB, nSB, threadIdx.x);
        return;
    }
    short* Wl = (short*)smem;
    stage_W(W, Wl, threadIdx.x);
    __syncthreads();
    gemm_tile(x, Wl, bias, h, (blockIdx.x - nHist) * 128, nRows, threadIdx.x);
}

__global__ __launch_bounds__(256)
void scan1_kernel(const int* __restrict__ cnt, int* __restrict__ off,
                  int* __restrict__ part, int n) {
    __shared__ int sh[256];
    int base = blockIdx.x * 1024;
    int t = threadIdx.x;
    int v[4]; int s = 0;
    #pragma unroll
    for (int i = 0; i < 4; ++i) {
        int idx = base + t * 4 + i;
        v[i] = (idx < n) ? cnt[idx] : 0;
        s += v[i];
    }
    sh[t] = s;
    __syncthreads();
    for (int d = 1; d < 256; d <<= 1) {
        int val = (t >= d) ? sh[t - d] : 0;
        __syncthreads();
        sh[t] += val;
        __syncthreads();
    }
    if (t == 255) part[blockIdx.x] = sh[255];
    int run = (t == 0) ? 0 : sh[t - 1];
    #pragma unroll
    for (int i = 0; i < 4; ++i) {
        int idx = base + t * 4 + i;
        if (idx < n) off[idx] = run;
        run += v[i];
    }
}

__global__ __launch_bounds__(256)
void scan2_kernel(int* __restrict__ part, int nPart) {
    __shared__ int sh[256];
    int t = threadIdx.x;
    int v[4]; int s = 0;
    #pragma unroll
    for (int i = 0; i < 4; ++i) {
        int idx = t * 4 + i;
        v[i] = (idx < nPart) ? part[idx] : 0;
        s += v[i];
    }
    sh[t] = s;
    __syncthreads();
    for (int d = 1; d < 256; d <<= 1) {
        int val = (t >= d) ? sh[t - d] : 0;
        __syncthreads();
        sh[t] += val;
        __syncthreads();
    }
    int run = (t == 0) ? 0 : sh[t - 1];
    #pragma unroll
    for (int i = 0; i < 4; ++i) {
        int idx = t * 4 + i;
        if (idx < nPart) part[idx] = run;
        run += v[i];
    }
}

__global__ __launch_bounds__(256)
void bfill_kernel(const int* __restrict__ src, const int* __restrict__ dst,
                  const float* __restrict__ w, const int* __restrict__ bases,
                  const int* __restrict__ part, int2* __restrict__ pack,
                  int nE, int NB, int nSB) {
    __shared__ int cur[MAX_NB];
    bfill_chunk(src, dst, w, bases, part, pack, cur,
                blockIdx.x, nE, NB, nSB, threadIdx.x);
}

__global__ __launch_bounds__(256)
void nsort_kernel(const int2* __restrict__ pack, const int* __restrict__ bases,
                  const int* __restrict__ part, int2* __restrict__ pack2,
                  int* __restrict__ off, int nRows, int nE, int NB, int nSB) {
    __shared__ int cnt[BKT_NODES];
    __shared__ int scn[BKT_NODES];
    nsort_bucket(pack, bases, part, pack2, off, cnt, scn,
                 blockIdx.x, nRows, nE, NB, nSB, threadIdx.x);
}

__global__ __launch_bounds__(256)
void ngather_kernel(const short* __restrict__ h, const int* __restrict__ off,
                    const int2* __restrict__ pack2, float* __restrict__ out,
                    int nNodes) {
    int wid = (blockIdx.x * 256 + threadIdx.x) >> 6;
    int lane = threadIdx.x & 63;
    if (wid >= nNodes) return;
    out[(size_t)wid * OUT_F + lane] =
        gather_node((const ushort*)h, pack2, off[wid], off[wid + 1], lane);
}

__global__ __launch_bounds__(256)
void scatter_kernel(const short* __restrict__ h, const int* __restrict__ src,
                    const int* __restrict__ dst, const float* __restrict__ w,
                    float* __restrict__ out, int nE) {
    int t = blockIdx.x * 256 + threadIdx.x;
    int c = t & 15;
    int stride = (gridDim.x * 256) >> 4;
    for (int e = t >> 4; e < nE; e += stride) {
        int s = src[e];
        int d = dst[e];
        float ww = w[e];
        float* op = out + (size_t)d * OUT_F + c * 4;
        const short* hp = h + (size_t)s * OUT_F + c * 4;
        unsafeAtomicAdd(op + 0, ww * bf2f(hp[0]));
        unsafeAtomicAdd(op + 1, ww * bf2f(hp[1]));
        unsafeAtomicAdd(op + 2, ww * bf2f(hp[2]));
        unsafeAtomicAdd(op + 3, ww * bf2f(hp[3]));
    }
}

static inline size_t align256(size_t x) { return (x + 255) & ~(size_t)255; }

extern "C" void kernel_launch(void* const* d_in, const int* in_sizes, int n_in,
                              void* d_out, int out_size, void* d_ws, size_t ws_size,
                              hipStream_t stream) {
    const float* x    = (const float*)d_in[0];
    const int*   esrc = (const int*)d_in[1];
    const int*   edst = (const int*)d_in[2];
    const float* ew   = (const float*)d_in[3];
    const float* W    = (const float*)d_in[4];
    const float* b    = (const float*)d_in[5];

    int nRows = in_sizes[0] / IN_F;   // 100000
    int nE    = in_sizes[1];          // 1600000

    int NB  = (nRows + BKT_NODES - 1) / BKT_NODES;   // 782
    int nSB = (nE + SORT_CHUNK - 1) / SORT_CHUNK;    // 391
    int nCnt = NB * nSB;                             // 305762
    int nPart = (nCnt + 1023) / 1024;                // 299

    // workspace layout
    char* p = (char*)d_ws;
    size_t hB    = align256((size_t)nRows * OUT_F * sizeof(short));
    size_t cntB  = align256((size_t)nCnt * sizeof(int));
    size_t basB  = align256((size_t)nCnt * sizeof(int));
    size_t partB = align256((size_t)nPart * sizeof(int));
    size_t packB = align256((size_t)nE * sizeof(int2));
    size_t offB  = align256((size_t)(nRows + 1) * sizeof(int));
    size_t need  = hB + cntB + basB + partB + 2 * packB + offB;

    short* h      = (short*)p;  p += hB;
    int*   counts = (int*)p;    p += cntB;
    int*   bases  = (int*)p;    p += basB;
    int*   part   = (int*)p;    p += partB;
    int2*  pack   = (int2*)p;   p += packB;
    int2*  pack2  = (int2*)p;   p += packB;
    int*   off    = (int*)p;

    float* out = (float*)d_out;

    bool ok = (ws_size >= need) && (NB <= MAX_NB) && (nPart <= 1024) &&
              (nRows < (1 << 17));
    if (!ok) {
        // minimal path: GEMM (no hist) + atomic scatter
        int fcBlocks = (nRows + 127) / 128;
        fc_bhist_kernel<<<fcBlocks, 256, 0, stream>>>(
            x, W, b, h, edst, counts, nRows, nE, NB, nSB, 0);
        hipMemsetAsync(out, 0, (size_t)out_size * sizeof(float), stream);
        scatter_kernel<<<4096, 256, 0, stream>>>(h, esrc, edst, ew, out, nE);
        return;
    }

    // try cooperative mega-kernel with runtime-validated grid size
    int dev = 0, numCU = 0, maxBpc = 0;
    hipGetDevice(&dev);
    hipDeviceGetAttribute(&numCU, hipDeviceAttributeMultiprocessorCount, dev);
    hipError_t occErr = hipOccupancyMaxActiveBlocksPerMultiprocessor(
        &maxBpc, (const void*)mega_kernel, 256, 0);
    int grid = 0;
    if (occErr == hipSuccess && maxBpc > 0 && numCU > 0)
        grid = min(GRID_MAX, maxBpc * numCU);

    hipError_t launchErr = hipErrorUnknown;
    if (grid >= 64) {
        void* kargs[] = {
            (void*)&x, (void*)&esrc, (void*)&edst, (void*)&ew,
            (void*)&W, (void*)&b,
            (void*)&h, (void*)&counts, (void*)&bases, (void*)&part,
            (void*)&pack, (void*)&pack2, (void*)&off, (void*)&out,
            (void*)&nRows, (void*)&nE, (void*)&NB, (void*)&nSB,
            (void*)&nCnt, (void*)&nPart
        };
        launchErr = hipLaunchCooperativeKernel((const void*)mega_kernel,
                                               dim3(grid), dim3(256),
                                               kargs, 0, stream);
    }
    if (launchErr == hipSuccess) return;

    // fallback: verified multi-kernel pipeline (round-8 structure)
    int fcBlocks = (nRows + 127) / 128;
    fc_bhist_kernel<<<nSB + fcBlocks, 256, 0, stream>>>(
        x, W, b, h, edst, counts, nRows, nE, NB, nSB, nSB);
    scan1_kernel<<<nPart, 256, 0, stream>>>(counts, bases, part, nCnt);
    scan2_kernel<<<1, 256, 0, stream>>>(part, nPart);
    bfill_kernel<<<nSB, 256, 0, stream>>>(esrc, edst, ew, bases, part,
                                          pack, nE, NB, nSB);
    nsort_kernel<<<NB, 256, 0, stream>>>(pack, bases, part, pack2, off,
                                         nRows, nE, NB, nSB);
    int gBlocks = (nRows * 64 + 255) / 256;
    ngather_kernel<<<gBlocks, 256, 0, stream>>>(h, off, pack2, out, nRows);
}

// Round 14
// 284.664 us; speedup vs baseline: 2.4240x; 2.4240x over previous
//
#include <hip/hip_runtime.h>

#define IN_F 256
#define OUT_F 64
#define SORT_CHUNK 4096
#define BKT_SHIFT 7
#define BKT_NODES 128
#define MAX_NB 1024

typedef __attribute__((ext_vector_type(8))) short short8;
typedef __attribute__((ext_vector_type(4))) float f32x4;

static __device__ __forceinline__ short f2bf(float f) {
    union { float f; unsigned u; } v; v.f = f;
    unsigned r = v.u + 0x7FFFu + ((v.u >> 16) & 1u);  // RNE
    return (short)(r >> 16);
}
static __device__ __forceinline__ float bf2f(short s) {
    return __int_as_float(((unsigned)(unsigned short)s) << 16);
}

// ---- shared device helpers ----

// stage W (fp32, row-major KxN) -> swizzled bf16 LDS (32 KB)
static __device__ __forceinline__ void stage_W(const float* __restrict__ W,
                                               short* Wl, int tid) {
    const int n0 = tid & 63;
    const int kb = tid >> 6;
    #pragma unroll
    for (int K0 = 0; K0 < 64; K0 += 8) {
        const int k0 = kb * 64 + K0;
        short8 v;
        #pragma unroll
        for (int j = 0; j < 8; ++j)
            v[j] = f2bf(W[(k0 + j) * OUT_F + n0]);
        *(short8*)((char*)Wl + n0 * 512 + (((k0 >> 3)) ^ (n0 & 7)) * 16) = v;
    }
}

// one 128-row GEMM tile (4 waves x 32 rows), Wl already staged
static __device__ __forceinline__ void gemm_tile(const float* __restrict__ x,
                                                 const short* Wl,
                                                 const float* __restrict__ bias,
                                                 short* __restrict__ h,
                                                 int rowbase, int nRows, int tid) {
    const int wv = tid >> 6;
    const int l  = tid & 63;
    const int lr = l & 15;
    const int kg = l >> 4;
    const int rb = rowbase + wv * 32;
    if (rb >= nRows) return;
    const int ar0 = min(rb + lr,      nRows - 1);
    const int ar1 = min(rb + 16 + lr, nRows - 1);
    const float* xp0 = x + (size_t)ar0 * IN_F + kg * 8;
    const float* xp1 = x + (size_t)ar1 * IN_F + kg * 8;

    f32x4 acc[2][4];
    #pragma unroll
    for (int m = 0; m < 2; ++m)
        #pragma unroll
        for (int n = 0; n < 4; ++n) acc[m][n] = (f32x4)0.f;

    #pragma unroll
    for (int kt = 0; kt < 8; ++kt) {
        const int K0 = kt * 32;
        float4 a0lo = *(const float4*)(xp0 + K0);
        float4 a0hi = *(const float4*)(xp0 + K0 + 4);
        float4 a1lo = *(const float4*)(xp1 + K0);
        float4 a1hi = *(const float4*)(xp1 + K0 + 4);

        short8 a0, a1;
        a0[0] = f2bf(a0lo.x); a0[1] = f2bf(a0lo.y);
        a0[2] = f2bf(a0lo.z); a0[3] = f2bf(a0lo.w);
        a0[4] = f2bf(a0hi.x); a0[5] = f2bf(a0hi.y);
        a0[6] = f2bf(a0hi.z); a0[7] = f2bf(a0hi.w);
        a1[0] = f2bf(a1lo.x); a1[1] = f2bf(a1lo.y);
        a1[2] = f2bf(a1lo.z); a1[3] = f2bf(a1lo.w);
        a1[4] = f2bf(a1hi.x); a1[5] = f2bf(a1hi.y);
        a1[6] = f2bf(a1hi.z); a1[7] = f2bf(a1hi.w);

        short8 bf[4];
        #pragma unroll
        for (int nt = 0; nt < 4; ++nt) {
            const int col = nt * 16 + lr;
            const int slot = (kt * 4 + kg) ^ (col & 7);
            bf[nt] = *(const short8*)((const char*)Wl + col * 512 + slot * 16);
        }
        #pragma unroll
        for (int nt = 0; nt < 4; ++nt) {
            acc[0][nt] = __builtin_amdgcn_mfma_f32_16x16x32_bf16(a0, bf[nt], acc[0][nt], 0, 0, 0);
            acc[1][nt] = __builtin_amdgcn_mfma_f32_16x16x32_bf16(a1, bf[nt], acc[1][nt], 0, 0, 0);
        }
    }

    #pragma unroll
    for (int m = 0; m < 2; ++m) {
        #pragma unroll
        for (int nt = 0; nt < 4; ++nt) {
            const int col = nt * 16 + lr;
            const float bb = bias[col];
            #pragma unroll
            for (int j = 0; j < 4; ++j) {
                const int r = rb + m * 16 + kg * 4 + j;
                if (r < nRows)
                    h[(size_t)r * OUT_F + col] = f2bf(acc[m][nt][j] + bb);
            }
        }
    }
}

static __device__ __forceinline__ void hist_chunk(const int* __restrict__ dst,
                                                  int* lh, int* __restrict__ counts,
                                                  int cb, int nE, int NB, int nSB,
                                                  int tid) {
    for (int b0 = tid; b0 < NB; b0 += 256) lh[b0] = 0;
    __syncthreads();
    const int base = cb * SORT_CHUNK;
    const int lim = min(nE, base + SORT_CHUNK);
    const int4* d4 = (const int4*)(dst + base);
    const int n4 = (lim - base) >> 2;
    for (int i = tid; i < n4; i += 256) {
        int4 v = d4[i];
        atomicAdd(&lh[v.x >> BKT_SHIFT], 1);
        atomicAdd(&lh[v.y >> BKT_SHIFT], 1);
        atomicAdd(&lh[v.z >> BKT_SHIFT], 1);
        atomicAdd(&lh[v.w >> BKT_SHIFT], 1);
    }
    for (int e = base + (n4 << 2) + tid; e < lim; e += 256)
        atomicAdd(&lh[dst[e] >> BKT_SHIFT], 1);
    __syncthreads();
    for (int b0 = tid; b0 < NB; b0 += 256)
        counts[b0 * nSB + cb] = lh[b0];
    __syncthreads();
}

// exclusive scan of part[0..nPart) (raw per-1024 totals) into LDS partS
static __device__ __forceinline__ void local_part_scan(
        const int* __restrict__ part, int nPart, int* partS, int* sh, int tid) {
    int v[4]; int sum = 0;
    #pragma unroll
    for (int i = 0; i < 4; ++i) {
        int idx = tid * 4 + i;
        v[i] = (idx < nPart) ? part[idx] : 0;
        sum += v[i];
    }
    sh[tid] = sum;
    __syncthreads();
    for (int d = 1; d < 256; d <<= 1) {
        int val = (tid >= d) ? sh[tid - d] : 0;
        __syncthreads();
        sh[tid] += val;
        __syncthreads();
    }
    int run = (tid == 0) ? 0 : sh[tid - 1];
    #pragma unroll
    for (int i = 0; i < 4; ++i) {
        partS[tid * 4 + i] = run;
        run += v[i];
    }
    __syncthreads();
}

// ---- kernels ----

// fused: blockIdx < nHist -> histogram chunk; else GEMM tile
__global__ __launch_bounds__(256, 4)
void fc_bhist_kernel(const float* __restrict__ x, const float* __restrict__ W,
                     const float* __restrict__ bias, short* __restrict__ h,
                     const int* __restrict__ dst, int* __restrict__ counts,
                     int nRows, int nE, int NB, int nSB, int nHist) {
    __shared__ __align__(16) char smem[32768];
    if ((int)blockIdx.x < nHist) {
        hist_chunk(dst, (int*)smem, counts, blockIdx.x, nE, NB, nSB, threadIdx.x);
        return;
    }
    short* Wl = (short*)smem;
    stage_W(W, Wl, threadIdx.x);
    __syncthreads();
    gemm_tile(x, Wl, bias, h, (blockIdx.x - nHist) * 128, nRows, threadIdx.x);
}

// per-1024-block exclusive scan; part[s] gets the RAW block total
__global__ __launch_bounds__(256)
void scan1_kernel(const int* __restrict__ cnt, int* __restrict__ off,
                  int* __restrict__ part, int n) {
    __shared__ int sh[256];
    int base = blockIdx.x * 1024;
    int t = threadIdx.x;
    int v[4]; int s = 0;
    #pragma unroll
    for (int i = 0; i < 4; ++i) {
        int idx = base + t * 4 + i;
        v[i] = (idx < n) ? cnt[idx] : 0;
        s += v[i];
    }
    sh[t] = s;
    __syncthreads();
    for (int d = 1; d < 256; d <<= 1) {
        int val = (t >= d) ? sh[t - d] : 0;
        __syncthreads();
        sh[t] += val;
        __syncthreads();
    }
    if (t == 255) part[blockIdx.x] = sh[255];
    int run = (t == 0) ? 0 : sh[t - 1];
    #pragma unroll
    for (int i = 0; i < 4; ++i) {
        int idx = base + t * 4 + i;
        if (idx < n) off[idx] = run;
        run += v[i];
    }
}

// bucket-ordered pack; does its own local scan of part
__global__ __launch_bounds__(256)
void bfill_kernel(const int* __restrict__ src, const int* __restrict__ dst,
                  const float* __restrict__ w, const int* __restrict__ bases,
                  const int* __restrict__ part, int2* __restrict__ pack,
                  int nE, int NB, int nSB, int nPart) {
    __shared__ int cur[MAX_NB];
    __shared__ int partS[MAX_NB];
    __shared__ int sh[256];
    const int tid = threadIdx.x;
    const int cb = blockIdx.x;
    local_part_scan(part, nPart, partS, sh, tid);
    for (int b0 = tid; b0 < NB; b0 += 256) {
        int idx = b0 * nSB + cb;
        cur[b0] = bases[idx] + partS[idx >> 10];
    }
    __syncthreads();
    const int base = cb * SORT_CHUNK;
    const int lim = min(nE, base + SORT_CHUNK);
    const int4* s4 = (const int4*)(src + base);
    const int4* d4 = (const int4*)(dst + base);
    const float4* w4 = (const float4*)(w + base);
    const int n4 = (lim - base) >> 2;
    for (int i = tid; i < n4; i += 256) {
        int4 s = s4[i]; int4 d = d4[i]; float4 ww = w4[i];
        int p0 = atomicAdd(&cur[d.x >> BKT_SHIFT], 1);
        pack[p0] = make_int2(s.x | ((d.x & (BKT_NODES - 1)) << 17), __float_as_int(ww.x));
        int p1 = atomicAdd(&cur[d.y >> BKT_SHIFT], 1);
        pack[p1] = make_int2(s.y | ((d.y & (BKT_NODES - 1)) << 17), __float_as_int(ww.y));
        int p2 = atomicAdd(&cur[d.z >> BKT_SHIFT], 1);
        pack[p2] = make_int2(s.z | ((d.z & (BKT_NODES - 1)) << 17), __float_as_int(ww.z));
        int p3 = atomicAdd(&cur[d.w >> BKT_SHIFT], 1);
        pack[p3] = make_int2(s.w | ((d.w & (BKT_NODES - 1)) << 17), __float_as_int(ww.w));
    }
    for (int e = base + (n4 << 2) + tid; e < lim; e += 256) {
        int d = dst[e];
        int p = atomicAdd(&cur[d >> BKT_SHIFT], 1);
        pack[p] = make_int2(src[e] | ((d & (BKT_NODES - 1)) << 17),
                            __float_as_int(w[e]));
    }
}

// node-sort within bucket; does its own local scan of part
__global__ __launch_bounds__(256)
void nsort_kernel(const int2* __restrict__ pack, const int* __restrict__ bases,
                  const int* __restrict__ part, int2* __restrict__ pack2,
                  int* __restrict__ off, int nRows, int nE, int NB, int nSB,
                  int nPart) {
    __shared__ int cnt[BKT_NODES];
    __shared__ int scn[BKT_NODES];
    __shared__ int partS[MAX_NB];
    __shared__ int sh[256];
    const int b = blockIdx.x;
    const int tid = threadIdx.x;
    local_part_scan(part, nPart, partS, sh, tid);

    const int i0 = b * nSB;
    const int segStart = bases[i0] + partS[i0 >> 10];
    int segEnd = nE;
    if (b + 1 < NB) {
        int i1 = (b + 1) * nSB;
        segEnd = bases[i1] + partS[i1 >> 10];
    }
    if (tid < BKT_NODES) cnt[tid] = 0;
    __syncthreads();
    {
        int e = segStart + tid;
        for (; e + 768 < segEnd; e += 1024) {
            int a0 = pack[e].x, a1 = pack[e + 256].x;
            int a2 = pack[e + 512].x, a3 = pack[e + 768].x;
            atomicAdd(&cnt[(a0 >> 17) & (BKT_NODES - 1)], 1);
            atomicAdd(&cnt[(a1 >> 17) & (BKT_NODES - 1)], 1);
            atomicAdd(&cnt[(a2 >> 17) & (BKT_NODES - 1)], 1);
            atomicAdd(&cnt[(a3 >> 17) & (BKT_NODES - 1)], 1);
        }
        for (; e < segEnd; e += 256)
            atomicAdd(&cnt[(pack[e].x >> 17) & (BKT_NODES - 1)], 1);
    }
    __syncthreads();
    if (tid < BKT_NODES) scn[tid] = cnt[tid];
    __syncthreads();
    for (int d = 1; d < BKT_NODES; d <<= 1) {
        int t = 0;
        if (tid < BKT_NODES && tid >= d) t = scn[tid - d];
        __syncthreads();
        if (tid < BKT_NODES) scn[tid] += t;
        __syncthreads();
    }
    const int node0 = b * BKT_NODES;
    const int ncnt = min(BKT_NODES, nRows - node0);
    if (tid < ncnt)
        off[node0 + tid] = segStart + scn[tid] - cnt[tid];
    if (tid == 0 && node0 + ncnt == nRows)
        off[nRows] = segEnd;
    __syncthreads();
    if (tid < BKT_NODES) cnt[tid] = segStart + scn[tid] - cnt[tid];
    __syncthreads();
    {
        int e = segStart + tid;
        for (; e + 768 < segEnd; e += 1024) {
            int2 p0 = pack[e], p1 = pack[e + 256];
            int2 p2 = pack[e + 512], p3 = pack[e + 768];
            int q0 = atomicAdd(&cnt[(p0.x >> 17) & (BKT_NODES - 1)], 1);
            pack2[q0] = make_int2(p0.x & 0x1FFFF, p0.y);
            int q1 = atomicAdd(&cnt[(p1.x >> 17) & (BKT_NODES - 1)], 1);
            pack2[q1] = make_int2(p1.x & 0x1FFFF, p1.y);
            int q2 = atomicAdd(&cnt[(p2.x >> 17) & (BKT_NODES - 1)], 1);
            pack2[q2] = make_int2(p2.x & 0x1FFFF, p2.y);
            int q3 = atomicAdd(&cnt[(p3.x >> 17) & (BKT_NODES - 1)], 1);
            pack2[q3] = make_int2(p3.x & 0x1FFFF, p3.y);
        }
        for (; e < segEnd; e += 256) {
            int2 p = pack[e];
            int q = atomicAdd(&cnt[(p.x >> 17) & (BKT_NODES - 1)], 1);
            pack2[q] = make_int2(p.x & 0x1FFFF, p.y);
        }
    }
}

// one wave per node
__global__ __launch_bounds__(256)
void ngather_kernel(const short* __restrict__ h, const int* __restrict__ off,
                    const int2* __restrict__ pack2, float* __restrict__ out,
                    int nNodes) {
    int wid = (blockIdx.x * 256 + threadIdx.x) >> 6;
    int lane = threadIdx.x & 63;
    if (wid >= nNodes) return;
    int e = off[wid], end = off[wid + 1];
    const ushort* hu = (const ushort*)h;
    float acc = 0.f;
    for (; e + 8 <= end; e += 8) {
        int2 pk[8];
        #pragma unroll
        for (int i = 0; i < 8; ++i) pk[i] = pack2[e + i];
        float hv[8];
        #pragma unroll
        for (int i = 0; i < 8; ++i)
            hv[i] = bf2f((short)hu[(size_t)pk[i].x * OUT_F + lane]);
        #pragma unroll
        for (int i = 0; i < 8; ++i)
            acc = fmaf(__int_as_float(pk[i].y), hv[i], acc);
    }
    for (; e + 4 <= end; e += 4) {
        int2 pk[4];
        #pragma unroll
        for (int i = 0; i < 4; ++i) pk[i] = pack2[e + i];
        #pragma unroll
        for (int i = 0; i < 4; ++i)
            acc = fmaf(__int_as_float(pk[i].y),
                       bf2f((short)hu[(size_t)pk[i].x * OUT_F + lane]), acc);
    }
    for (; e < end; ++e) {
        int2 p = pack2[e];
        acc = fmaf(__int_as_float(p.y),
                   bf2f((short)hu[(size_t)p.x * OUT_F + lane]), acc);
    }
    out[(size_t)wid * OUT_F + lane] = acc;
}

// fallback (atomic) scatter
__global__ __launch_bounds__(256)
void scatter_kernel(const short* __restrict__ h, const int* __restrict__ src,
                    const int* __restrict__ dst, const float* __restrict__ w,
                    float* __restrict__ out, int nE) {
    int t = blockIdx.x * 256 + threadIdx.x;
    int c = t & 15;
    int stride = (gridDim.x * 256) >> 4;
    for (int e = t >> 4; e < nE; e += stride) {
        int s = src[e];
        int d = dst[e];
        float ww = w[e];
        float* op = out + (size_t)d * OUT_F + c * 4;
        const short* hp = h + (size_t)s * OUT_F + c * 4;
        unsafeAtomicAdd(op + 0, ww * bf2f(hp[0]));
        unsafeAtomicAdd(op + 1, ww * bf2f(hp[1]));
        unsafeAtomicAdd(op + 2, ww * bf2f(hp[2]));
        unsafeAtomicAdd(op + 3, ww * bf2f(hp[3]));
    }
}

static inline size_t align256(size_t x) { return (x + 255) & ~(size_t)255; }

extern "C" void kernel_launch(void* const* d_in, const int* in_sizes, int n_in,
                              void* d_out, int out_size, void* d_ws, size_t ws_size,
                              hipStream_t stream) {
    const float* x    = (const float*)d_in[0];
    const int*   esrc = (const int*)d_in[1];
    const int*   edst = (const int*)d_in[2];
    const float* ew   = (const float*)d_in[3];
    const float* W    = (const float*)d_in[4];
    const float* b    = (const float*)d_in[5];

    int nRows = in_sizes[0] / IN_F;   // 100000
    int nE    = in_sizes[1];          // 1600000

    int NB  = (nRows + BKT_NODES - 1) / BKT_NODES;   // 782
    int nSB = (nE + SORT_CHUNK - 1) / SORT_CHUNK;    // 391
    int nCnt = NB * nSB;                             // 305762
    int nPart = (nCnt + 1023) / 1024;                // 299

    // workspace layout
    char* p = (char*)d_ws;
    size_t hB    = align256((size_t)nRows * OUT_F * sizeof(short));
    size_t cntB  = align256((size_t)nCnt * sizeof(int));
    size_t basB  = align256((size_t)nCnt * sizeof(int));
    size_t partB = align256((size_t)nPart * sizeof(int));
    size_t packB = align256((size_t)nE * sizeof(int2));
    size_t offB  = align256((size_t)(nRows + 1) * sizeof(int));
    size_t need  = hB + cntB + basB + partB + 2 * packB + offB;

    short* h      = (short*)p;  p += hB;
    int*   counts = (int*)p;    p += cntB;
    int*   bases  = (int*)p;    p += basB;
    int*   part   = (int*)p;    p += partB;
    int2*  pack   = (int2*)p;   p += packB;
    int2*  pack2  = (int2*)p;   p += packB;
    int*   off    = (int*)p;

    float* out = (float*)d_out;

    bool ok = (ws_size >= need) && (NB <= MAX_NB) && (nPart <= 1024) &&
              (nRows < (1 << 17));
    int fcBlocks = (nRows + 127) / 128;   // 782

    if (!ok) {
        fc_bhist_kernel<<<fcBlocks, 256, 0, stream>>>(
            x, W, b, h, edst, counts, nRows, nE, NB, nSB, 0);
        hipMemsetAsync(out, 0, (size_t)out_size * sizeof(float), stream);
        scatter_kernel<<<4096, 256, 0, stream>>>(h, esrc, edst, ew, out, nE);
        return;
    }

    // verified multi-kernel pipeline (round-8 structure, scan2 folded into
    // consumers as LDS-local scans)
    fc_bhist_kernel<<<nSB + fcBlocks, 256, 0, stream>>>(
        x, W, b, h, edst, counts, nRows, nE, NB, nSB, nSB);
    scan1_kernel<<<nPart, 256, 0, stream>>>(counts, bases, part, nCnt);
    bfill_kernel<<<nSB, 256, 0, stream>>>(esrc, edst, ew, bases, part,
                                          pack, nE, NB, nSB, nPart);
    nsort_kernel<<<NB, 256, 0, stream>>>(pack, bases, part, pack2, off,
                                         nRows, nE, NB, nSB, nPart);
    int gBlocks = (nRows * 64 + 255) / 256;
    ngather_kernel<<<gBlocks, 256, 0, stream>>>(h, off, pack2, out, nRows);
}